// Round 9
// baseline (601.736 us; speedup 1.0000x reference)
//
#include <hip/hip_runtime.h>
#include <math.h>

using u16 = unsigned short;
using u32 = unsigned int;
using u64 = unsigned long long;

typedef __bf16 bf16x8 __attribute__((ext_vector_type(8)));
typedef short  s16x8  __attribute__((ext_vector_type(8)));
typedef float  f32x4  __attribute__((ext_vector_type(4)));

__device__ __forceinline__ float b2f(u16 u){
  union { u32 i; float f; } x; x.i = ((u32)u) << 16; return x.f;
}
__device__ __forceinline__ u16 f2b(float f){   // round-to-nearest-even
  union { float f; u32 i; } x; x.f = f;
  u32 i = x.i;
  u32 r = (i + 0x7fffu + ((i >> 16) & 1u)) >> 16;
  return (u16)r;
}
__device__ __forceinline__ f32x4 mfma16(s16x8 a, s16x8 b, f32x4 c){
  return __builtin_amdgcn_mfma_f32_16x16x32_bf16(
      __builtin_bit_cast(bf16x8, a), __builtin_bit_cast(bf16x8, b), c, 0, 0, 0);
}
__device__ __forceinline__ u64 shfl_xor_u64(u64 v, int m){
  int lo = __shfl_xor((int)(u32)v, m);
  int hi = __shfl_xor((int)(u32)(v >> 32), m);
  return ((u64)(u32)hi << 32) | (u32)lo;
}
__device__ __forceinline__ u64 umin64(u64 a, u64 b){ return a < b ? a : b; }
__device__ __forceinline__ u64 packmin(float v, int idx){
  u32 b = __float_as_uint(v);
  b = (b & 0x80000000u) ? ~b : (b | 0x80000000u);
  return ((u64)b << 32) | (u32)idx;
}

// ---------------- canary ----------------
__global__ __launch_bounds__(256) void canary_k(float* out, float code){
  out[threadIdx.x] = code;
}

// ---------------- fused prep: 6 transposed weight splits + cb split ----------------
__global__ __launch_bounds__(256) void prep_weights(
    const float* __restrict__ w1, const float* __restrict__ w2, const float* __restrict__ w3,
    const float* __restrict__ dw1, const float* __restrict__ dw2, const float* __restrict__ dw3,
    const float* __restrict__ cb,
    u16* __restrict__ o1h, u16* __restrict__ o1l, u16* __restrict__ o2h, u16* __restrict__ o2l,
    u16* __restrict__ o3h, u16* __restrict__ o3l, u16* __restrict__ o4h, u16* __restrict__ o4l,
    u16* __restrict__ o5h, u16* __restrict__ o5l, u16* __restrict__ o6h, u16* __restrict__ o6l,
    u16* __restrict__ cbh, u16* __restrict__ cbl)
{
  size_t o = (size_t)blockIdx.x * 256 + threadIdx.x;
  if (o >= 1155072){                       // cb segment: plain elementwise split
    size_t e = o - 1155072;
    if (e >= 1048576) return;
    float v = cb[e];
    u16 h = f2b(v);
    cbh[e] = h;
    cbl[e] = f2b(v - b2f(h));
    return;
  }
  const float* src; u16 *hi, *lo; int K, N, Kp; size_t base;
  if      (o <  425984){ src=w1;  hi=o1h; lo=o1l; K=784; N=512; Kp=832; base=0; }
  else if (o <  557056){ src=w2;  hi=o2h; lo=o2l; K=512; N=256; Kp=512; base=425984; }
  else if (o <  589824){ src=w3;  hi=o3h; lo=o3l; K=256; N=128; Kp=256; base=557056; }
  else if (o <  622592){ src=dw1; hi=o4h; lo=o4l; K=128; N=256; Kp=128; base=589824; }
  else if (o <  753664){ src=dw2; hi=o5h; lo=o5l; K=256; N=512; Kp=256; base=622592; }
  else                 { src=dw3; hi=o6h; lo=o6l; K=512; N=784; Kp=512; base=753664; }
  size_t e = o - base;
  int n = (int)(e / Kp), kp = (int)(e % Kp);
  u16 h = 0, l = 0;
  if (kp < K){
    float v = src[(size_t)kp * N + n];
    h = f2b(v);
    l = f2b(v - b2f(h));
  }
  hi[e] = h; lo[e] = l;
}

// ---------------- fused norms: q2 (z rows) + t2 (cb rows) ----------------
__global__ __launch_bounds__(256) void norms_all(const float* __restrict__ z, const float* __restrict__ cb,
                                                 float* __restrict__ q2, float* __restrict__ t2){
  int i = blockIdx.x * 256 + threadIdx.x;   // < 24576
  const float* src; float* dst;
  if (i < 16384){ src = z + (size_t)i * 128; dst = q2 + i; }
  else { int j = i - 16384; src = cb + (size_t)j * 128; dst = t2 + j; }
  const float4* r = (const float4*)src;
  float s = 0.f;
  for (int k = 0; k < 32; k++){
    float4 p = r[k];
    s += p.x * p.x + p.y * p.y + p.z * p.z + p.w * p.w;
  }
  *dst = s;
}

// ---------------- MFMA GEMM, A = f32 with on-the-fly hi/lo split ----------------
// 3 products: Ahi*Bhi + Ahi*Blo + Alo*Bhi.
// ACT: 0 none, 1 relu, 2 sigmoid(relu). OUTP: 0 f32; 1 f32 + hi/lo planes; 2 bf16 only.
template<int ACT, int OUTP>
__global__ __launch_bounds__(256, 2) void gemm_af32(
    const float* __restrict__ A, const u16* __restrict__ B0, const u16* __restrict__ B1,
    const float* __restrict__ bias, float* __restrict__ Cf,
    u16* __restrict__ P0, u16* __restrict__ P1,
    int Astr, int KLIM, int Kp, int KT, int N, int nRowsB)
{
  __shared__ __align__(16) u16 Ah[128][72];
  __shared__ __align__(16) u16 Al[128][72];
  __shared__ __align__(16) u16 Bh[128][72];
  __shared__ __align__(16) u16 Bl[128][72];
  const int tid = threadIdx.x;
  const int m0 = blockIdx.y * 128, n0 = blockIdx.x * 128;
  const int wave = tid >> 6, lane = tid & 63;
  const int wm = (wave >> 1) * 64, wn = (wave & 1) * 64;
  const int quad = lane >> 4, l15 = lane & 15;
  f32x4 acc[4][4] = {};

  for (int kt = 0; kt < KT; ++kt){
    const int kb = kt * 64;
    #pragma unroll
    for (int c = 0; c < 8; c++){            // stage A: 128 x 64 f32, split hi/lo
      int idx = c * 256 + tid;
      int r = idx >> 4, c4 = (idx & 15) * 4;
      float4 v = make_float4(0.f, 0.f, 0.f, 0.f);
      if (kb + c4 < KLIM)
        v = *(const float4*)(A + (size_t)(m0 + r) * Astr + kb + c4);
      ushort4 h, l;
      h.x = f2b(v.x); l.x = f2b(v.x - b2f(h.x));
      h.y = f2b(v.y); l.y = f2b(v.y - b2f(h.y));
      h.z = f2b(v.z); l.z = f2b(v.z - b2f(h.z));
      h.w = f2b(v.w); l.w = f2b(v.w - b2f(h.w));
      *(ushort4*)&Ah[r][c4] = h;
      *(ushort4*)&Al[r][c4] = l;
    }
    #pragma unroll
    for (int c = 0; c < 4; c++){            // stage B planes: 128 x 64 u16 each
      int idx = c * 256 + tid;
      int r = idx >> 3, col = (idx & 7) * 8;
      int rb = n0 + r; rb = rb < nRowsB ? rb : nRowsB - 1;
      *(uint4*)&Bh[r][col] = *(const uint4*)(B0 + (size_t)rb * Kp + kb + col);
      *(uint4*)&Bl[r][col] = *(const uint4*)(B1 + (size_t)rb * Kp + kb + col);
    }
    __syncthreads();
    #pragma unroll
    for (int kh = 0; kh < 2; ++kh){
      s16x8 ah[4], al[4], bh[4], bl[4];
      #pragma unroll
      for (int t4 = 0; t4 < 4; t4++){
        ah[t4] = *(const s16x8*)&Ah[wm + t4 * 16 + l15][kh * 32 + quad * 8];
        al[t4] = *(const s16x8*)&Al[wm + t4 * 16 + l15][kh * 32 + quad * 8];
        bh[t4] = *(const s16x8*)&Bh[wn + t4 * 16 + l15][kh * 32 + quad * 8];
        bl[t4] = *(const s16x8*)&Bl[wn + t4 * 16 + l15][kh * 32 + quad * 8];
      }
      #pragma unroll
      for (int mt = 0; mt < 4; mt++)
        #pragma unroll
        for (int nt = 0; nt < 4; nt++){
          acc[mt][nt] = mfma16(ah[mt], bh[nt], acc[mt][nt]);
          acc[mt][nt] = mfma16(ah[mt], bl[nt], acc[mt][nt]);
          acc[mt][nt] = mfma16(al[mt], bh[nt], acc[mt][nt]);
        }
    }
    __syncthreads();
  }

  float bvs[4]; int cols[4];
  #pragma unroll
  for (int nt = 0; nt < 4; nt++){
    int cN = n0 + wn + nt * 16 + l15;
    cols[nt] = cN;
    int cc = cN < N ? cN : N - 1;
    bvs[nt] = bias[cc];
  }
  #pragma unroll
  for (int mt = 0; mt < 4; mt++){
    int rbase = m0 + wm + mt * 16 + quad * 4;
    #pragma unroll
    for (int nt = 0; nt < 4; nt++){
      if (cols[nt] < N){
        #pragma unroll
        for (int r = 0; r < 4; r++){
          float v = acc[mt][nt][r] + bvs[nt];
          if (ACT >= 1) v = v > 0.f ? v : 0.f;
          if (ACT == 2) v = 1.f / (1.f + expf(-v));
          size_t off = (size_t)(rbase + r) * N + cols[nt];
          if (OUTP == 2){
            P0[off] = f2b(v);
          } else {
            Cf[off] = v;
            if (OUTP == 1){
              u16 h = f2b(v);
              P0[off] = h;
              P1[off] = f2b(v - b2f(h));
            }
          }
        }
      }
    }
  }
}

// ---------------- dist v5: pipelined barrier-free j-sweep ----------------
// grid (4 strips, 128 i-tiles); each block sweeps 16 j-tiles of 128 (strip stride 2048).
// Slice-level B double-buffer; epilogue of tile jt-1 runs between slice-0 load issue
// and slice-0 MFMAs of tile jt (covers load latency with VALU). acc re-inits via C=0.
struct BFrags { s16x8 h[4], l[4]; };

__device__ __forceinline__ void load_slice(
    const u16* __restrict__ Bh, const u16* __restrict__ Bl,
    int j0, int wn, int l15, int quad, int kb, int kh, BFrags& f)
{
  #pragma unroll
  for (int nt = 0; nt < 4; nt++){
    size_t off = (size_t)(j0 + wn + nt * 16 + l15) * 128 + kb * 64 + kh * 32 + quad * 8;
    f.h[nt] = *(const s16x8*)(Bh + off);
    f.l[nt] = *(const s16x8*)(Bl + off);
  }
}

template<bool FIRST>
__device__ __forceinline__ void mfma_slice(
    const s16x8 zh[4], const s16x8 zl[4], const BFrags& f, f32x4 acc[4][4])
{
  #pragma unroll
  for (int mt = 0; mt < 4; mt++)
    #pragma unroll
    for (int nt = 0; nt < 4; nt++){
      f32x4 c;
      if (FIRST){ c.x = 0.f; c.y = 0.f; c.z = 0.f; c.w = 0.f; }
      else c = acc[mt][nt];
      c = mfma16(zh[mt], f.h[nt], c);
      c = mfma16(zh[mt], f.l[nt], c);
      c = mfma16(zl[mt], f.h[nt], c);
      c = mfma16(zl[mt], f.l[nt], c);
      acc[mt][nt] = c;
    }
}

__global__ __launch_bounds__(256, 1) void dist3(
    const u16* __restrict__ Zh, const u16* __restrict__ Zl,
    const u16* __restrict__ Bh, const u16* __restrict__ Bl,
    const float* __restrict__ q2, const float* __restrict__ t2,
    u64* __restrict__ rowp, u64* __restrict__ colp)
{
  __shared__ u64 sRow[2][128];
  const int tid = threadIdx.x;
  const int i0 = blockIdx.y * 128;
  const int strip = blockIdx.x;
  const int wave = tid >> 6, lane = tid & 63;
  const int wm = (wave >> 1) * 64, wn = (wave & 1) * 64;
  const int quad = lane >> 4, l15 = lane & 15;

  // z fragments, loaded once: [slice][mt], slice = kb*2+kh
  s16x8 zh[4][4], zl[4][4];
  #pragma unroll
  for (int kb = 0; kb < 2; kb++)
    #pragma unroll
    for (int kh = 0; kh < 2; kh++)
      #pragma unroll
      for (int mt = 0; mt < 4; mt++){
        size_t off = (size_t)(i0 + wm + mt * 16 + l15) * 128 + kb * 64 + kh * 32 + quad * 8;
        zh[kb * 2 + kh][mt] = *(const s16x8*)(Zh + off);
        zl[kb * 2 + kh][mt] = *(const s16x8*)(Zl + off);
      }
  float qv[4][4];
  #pragma unroll
  for (int mt = 0; mt < 4; mt++)
    #pragma unroll
    for (int r = 0; r < 4; r++)
      qv[mt][r] = q2[i0 + wm + mt * 16 + quad * 4 + r];

  u64 rowm[4][4];
  #pragma unroll
  for (int mt = 0; mt < 4; mt++)
    #pragma unroll
    for (int r = 0; r < 4; r++) rowm[mt][r] = ~0ULL;

  f32x4 acc[4][4];
  BFrags fb[2];
  const int jbase = strip * 2048;
  load_slice(Bh, Bl, jbase, wn, l15, quad, 0, 0, fb[0]);   // preload tile0 slice0

  for (int jt = 0; jt < 16; ++jt){
    const int j0 = jbase + jt * 128;
    const int j0n = jbase + ((jt + 1) & 15) * 128;

    load_slice(Bh, Bl, j0, wn, l15, quad, 0, 1, fb[1]);    // slice1 prefetch

    // ---- epilogue for tile jt-1 (acc still holds it); covers slice0/1 load latency
    if (jt > 0){
      const int j0p = j0 - 128;
      float t2v[4]; int gj[4];
      #pragma unroll
      for (int nt = 0; nt < 4; nt++){
        gj[nt] = j0p + wn + nt * 16 + l15;
        t2v[nt] = t2[gj[nt]];
      }
      #pragma unroll
      for (int mt = 0; mt < 4; mt++){
        #pragma unroll
        for (int r = 0; r < 4; r++){
          float qq = qv[mt][r];
          float rbest = (qq - 2.f * acc[mt][0][r]) + t2v[0];
          int   ridx  = gj[0];
          #pragma unroll
          for (int nt = 1; nt < 4; nt++){
            float v = (qq - 2.f * acc[mt][nt][r]) + t2v[nt];
            if (v < rbest){ rbest = v; ridx = gj[nt]; }
          }
          rowm[mt][r] = umin64(rowm[mt][r], packmin(rbest, ridx));
        }
      }
      #pragma unroll
      for (int nt = 0; nt < 4; nt++){
        float cbest = 3.4e38f; int cidx = 0;
        #pragma unroll
        for (int mt = 0; mt < 4; mt++){
          #pragma unroll
          for (int r = 0; r < 4; r++){
            float vc = (t2v[nt] - 2.f * acc[mt][nt][r]) + qv[mt][r];
            if (vc < cbest){ cbest = vc; cidx = i0 + wm + mt * 16 + quad * 4 + r; }
          }
        }
        u64 p = packmin(cbest, cidx);
        p = umin64(p, shfl_xor_u64(p, 16));
        p = umin64(p, shfl_xor_u64(p, 32));
        if (quad == 0)
          colp[(size_t)(blockIdx.y * 2 + (wave >> 1)) * 8192 + gj[nt]] = p;
      }
    }

    // ---- MFMA slices (slice0 starts from C=0), interleaved with next-slice loads
    mfma_slice<true >(zh[0], zl[0], fb[0], acc);
    load_slice(Bh, Bl, j0, wn, l15, quad, 1, 0, fb[0]);    // slice2
    mfma_slice<false>(zh[1], zl[1], fb[1], acc);
    load_slice(Bh, Bl, j0, wn, l15, quad, 1, 1, fb[1]);    // slice3
    mfma_slice<false>(zh[2], zl[2], fb[0], acc);
    load_slice(Bh, Bl, j0n, wn, l15, quad, 0, 0, fb[0]);   // next tile slice0
    mfma_slice<false>(zh[3], zl[3], fb[1], acc);
  }

  // ---- final tile epilogue (jt = 15)
  {
    const int j0p = jbase + 15 * 128;
    float t2v[4]; int gj[4];
    #pragma unroll
    for (int nt = 0; nt < 4; nt++){
      gj[nt] = j0p + wn + nt * 16 + l15;
      t2v[nt] = t2[gj[nt]];
    }
    #pragma unroll
    for (int mt = 0; mt < 4; mt++){
      #pragma unroll
      for (int r = 0; r < 4; r++){
        float qq = qv[mt][r];
        float rbest = (qq - 2.f * acc[mt][0][r]) + t2v[0];
        int   ridx  = gj[0];
        #pragma unroll
        for (int nt = 1; nt < 4; nt++){
          float v = (qq - 2.f * acc[mt][nt][r]) + t2v[nt];
          if (v < rbest){ rbest = v; ridx = gj[nt]; }
        }
        rowm[mt][r] = umin64(rowm[mt][r], packmin(rbest, ridx));
      }
    }
    #pragma unroll
    for (int nt = 0; nt < 4; nt++){
      float cbest = 3.4e38f; int cidx = 0;
      #pragma unroll
      for (int mt = 0; mt < 4; mt++){
        #pragma unroll
        for (int r = 0; r < 4; r++){
          float vc = (t2v[nt] - 2.f * acc[mt][nt][r]) + qv[mt][r];
          if (vc < cbest){ cbest = vc; cidx = i0 + wm + mt * 16 + quad * 4 + r; }
        }
      }
      u64 p = packmin(cbest, cidx);
      p = umin64(p, shfl_xor_u64(p, 16));
      p = umin64(p, shfl_xor_u64(p, 32));
      if (quad == 0)
        colp[(size_t)(blockIdx.y * 2 + (wave >> 1)) * 8192 + gj[nt]] = p;
    }
  }

  // row final reduce (single barrier at kernel end)
  #pragma unroll
  for (int mt = 0; mt < 4; mt++)
    #pragma unroll
    for (int r = 0; r < 4; r++){
      u64 p = rowm[mt][r];
      p = umin64(p, shfl_xor_u64(p, 1));
      p = umin64(p, shfl_xor_u64(p, 2));
      p = umin64(p, shfl_xor_u64(p, 4));
      p = umin64(p, shfl_xor_u64(p, 8));
      rowm[mt][r] = p;
    }
  if (l15 == 0){
    #pragma unroll
    for (int mt = 0; mt < 4; mt++)
      #pragma unroll
      for (int r = 0; r < 4; r++)
        sRow[wave & 1][wm + mt * 16 + quad * 4 + r] = rowm[mt][r];
  }
  __syncthreads();
  if (tid < 128)
    rowp[(size_t)strip * 16384 + i0 + tid] = umin64(sRow[0][tid], sRow[1][tid]);
}

// ---------------- merged final reduces + gathers ----------------
__global__ __launch_bounds__(256) void reduce_rc(
    const u64* __restrict__ rowp, const u64* __restrict__ colp,
    const float* __restrict__ cb, const float* __restrict__ zenc,
    float* __restrict__ zdec, float* __restrict__ zembd, int* __restrict__ rowidx)
{
  int tid = threadIdx.x;
  __shared__ u64 s[4][64];
  __shared__ int sidx[64];
  if (blockIdx.x < 256){
    int base = blockIdx.x * 64;
    int n = base + (tid & 63);
    u64 best = ~0ULL;
    for (int p = tid >> 6; p < 4; p += 4)
      best = umin64(best, rowp[(size_t)p * 16384 + n]);
    s[tid >> 6][tid & 63] = best;
    __syncthreads();
    if (tid < 64){
      u64 b = umin64(umin64(s[0][tid], s[1][tid]), umin64(s[2][tid], s[3][tid]));
      int idx = (int)(b & 0xffffffffULL);
      idx = idx < 0 ? 0 : (idx > 8191 ? 8191 : idx);
      sidx[tid] = idx;
      rowidx[base + tid] = idx;
    }
    __syncthreads();
    for (int q = 0; q < 32; q++){
      int e = q * 256 + tid; int r = e >> 7, c = e & 127;
      zdec[(size_t)(base + r) * 128 + c] = cb[(size_t)sidx[r] * 128 + c];
    }
  } else {
    int base = (blockIdx.x - 256) * 64;
    int n = base + (tid & 63);
    u64 best = ~0ULL;
    for (int p = tid >> 6; p < 256; p += 4)
      best = umin64(best, colp[(size_t)p * 8192 + n]);
    s[tid >> 6][tid & 63] = best;
    __syncthreads();
    if (tid < 64){
      u64 b = umin64(umin64(s[0][tid], s[1][tid]), umin64(s[2][tid], s[3][tid]));
      int idx = (int)(b & 0xffffffffULL);
      idx = idx < 0 ? 0 : (idx > 16383 ? 16383 : idx);
      sidx[tid] = idx;
    }
    __syncthreads();
    for (int q = 0; q < 32; q++){
      int e = q * 256 + tid; int r = e >> 7, c = e & 127;
      zembd[(size_t)(base + r) * 128 + c] = zenc[(size_t)sidx[r] * 128 + c];
    }
  }
}

__global__ __launch_bounds__(256) void gather_xrec(
    const u16* __restrict__ xdecb, const int* __restrict__ rowidx, float* __restrict__ xrec)
{
  size_t o = (size_t)blockIdx.x * 256 + threadIdx.x;  // < 16384*784
  int row = (int)(o / 784), c = (int)(o % 784);
  int idx = rowidx[row];
  idx = idx < 0 ? 0 : (idx > 8191 ? 8191 : idx);
  xrec[o] = b2f(xdecb[(size_t)idx * 784 + c]);
}

// ---------------- launcher ----------------
extern "C" void kernel_launch(void* const* d_in, const int* in_sizes, int n_in,
                              void* d_out, int out_size, void* d_ws, size_t ws_size,
                              hipStream_t stream){
  const float* X   = (const float*)d_in[0];
  const float* w1  = (const float*)d_in[1];  const float* b1  = (const float*)d_in[2];
  const float* w2  = (const float*)d_in[3];  const float* b2  = (const float*)d_in[4];
  const float* w3  = (const float*)d_in[5];  const float* b3  = (const float*)d_in[6];
  const float* cb  = (const float*)d_in[7];
  const float* dw1 = (const float*)d_in[8];  const float* db1 = (const float*)d_in[9];
  const float* dw2 = (const float*)d_in[10]; const float* db2 = (const float*)d_in[11];
  const float* dw3 = (const float*)d_in[12]; const float* db3 = (const float*)d_in[13];

  float* out   = (float*)d_out;
  float* xrec  = out;                        // [16384*784] f32
  float* zenc  = out + 12845056;             // [16384*128]
  float* zdec  = zenc + 2097152;             // [16384*128]
  float* zembd = zdec + 2097152;             // [8192*128]

  const size_t NEEDED = 22085632;
  if (ws_size < NEEDED){
    canary_k<<<1, 256, 0, stream>>>(out, 1000.0f + (float)(ws_size >> 20));
    return;
  }

  // scratch inside d_out's xrec region (51.4 MB; xrec written only at the very end)
  char* ob = (char*)d_out;
  float* h1   = (float*)(ob + 0);            // 16384*512*4 = 33,554,432  [enc1 -> enc2]
  float* g2   = (float*)(ob + 0);            // 8192*512*4  = 16,777,216  [dec2 -> dec3]
  u16*   zhi  = (u16*)(ob + 33554432);       // 4,194,304                 [enc3 -> dist]
  u16*   zlo  = (u16*)(ob + 37748736);       // 4,194,304
  u16*   cbhi = (u16*)(ob + 41943040);       // 2,097,152                 [prep -> dist]
  u16*   cblo = (u16*)(ob + 44040192);       // 2,097,152 -> 46,137,344 <= 51,380,224 OK

  char* w = (char*)d_ws;
  u16* W1Th = (u16*)(w + 0);        u16* W1Tl = (u16*)(w + 851968);
  u16* W2Th = (u16*)(w + 1703936);  u16* W2Tl = (u16*)(w + 1966080);
  u16* W3Th = (u16*)(w + 2228224);  u16* W3Tl = (u16*)(w + 2293760);
  u16* D1Th = (u16*)(w + 2359296);  u16* D1Tl = (u16*)(w + 2424832);
  u16* D2Th = (u16*)(w + 2490368);  u16* D2Tl = (u16*)(w + 2752512);
  u16* D3Th = (u16*)(w + 3014656);  u16* D3Tl = (u16*)(w + 3817472);   // -> 4,620,288
  float* q2f = (float*)(w + 4620288);        // 65,536
  float* t2f = (float*)(w + 4685824);        // 32,768
  int*  rowi = (int*)(w + 4718592);          // 65,536
  u64*  rowp = (u64*)(w + 4784128);          // 4*16384*8 = 524,288 -> 5,308,416
  // region R = [5,308,416, 22,085,632): h2 -> colp(256 partials) -> (g1, xdecb)
  float* h2   = (float*)(w + 5308416);       // 16384*256*4 = 16,777,216
  u64*  colp  = (u64*)(w + 5308416);         // 256*8192*8 = 16,777,216 -> 22,085,632
  float* g1   = (float*)(w + 13697024);      // 8192*256*4 = 8,388,608 (after colp consumed)
  u16*  xdecb = (u16*)(w + 5308416);         // 8192*784*2 = 12,845,056 (after colp consumed)

  // prep (weights + codebook split, one kernel)
  prep_weights<<<8608, 256, 0, stream>>>(w1, w2, w3, dw1, dw2, dw3, cb,
      W1Th, W1Tl, W2Th, W2Tl, W3Th, W3Tl, D1Th, D1Tl, D2Th, D2Tl, D3Th, D3Tl, cbhi, cblo);

  // encoder (unchunked; 3-product split, f32 A staged+split on the fly)
  gemm_af32<1, 0><<<dim3(4, 128), 256, 0, stream>>>(X,  W1Th, W1Tl, b1, h1,   nullptr, nullptr, 784, 784, 832, 13, 512, 512);
  gemm_af32<1, 0><<<dim3(2, 128), 256, 0, stream>>>(h1, W2Th, W2Tl, b2, h2,   nullptr, nullptr, 512, 512, 512,  8, 256, 256);
  gemm_af32<0, 1><<<dim3(1, 128), 256, 0, stream>>>(h2, W3Th, W3Tl, b3, zenc, zhi,     zlo,     256, 256, 256,  4, 128, 128);

  // norms
  norms_all<<<96, 256, 0, stream>>>(zenc, cb, q2f, t2f);

  // fused distance + dual argmin (4 products, z in registers, pipelined barrier-free sweep)
  dist3<<<dim3(4, 128), 256, 0, stream>>>(zhi, zlo, cbhi, cblo, q2f, t2f, rowp, colp);

  // merged reduces + gathers
  reduce_rc<<<384, 256, 0, stream>>>(rowp, colp, cb, zenc, zdec, zembd, rowi);

  // decoder over 8192 codebook rows
  gemm_af32<1, 0><<<dim3(2, 64), 256, 0, stream>>>(cb, D1Th, D1Tl, db1, g1, nullptr, nullptr, 128, 128, 128, 2, 256, 256);
  gemm_af32<1, 0><<<dim3(4, 64), 256, 0, stream>>>(g1, D2Th, D2Tl, db2, g2, nullptr, nullptr, 256, 256, 256, 4, 512, 512);
  gemm_af32<2, 2><<<dim3(7, 64), 256, 0, stream>>>(g2, D3Th, D3Tl, db3, nullptr, xdecb, nullptr, 512, 512, 512, 8, 784, 784);

  gather_xrec<<<50176, 256, 0, stream>>>(xdecb, rowi, xrec);
}